// Round 24
// baseline (173.147 us; speedup 1.0000x reference)
//
#include <hip/hip_runtime.h>
#include <hip/hip_bf16.h>
#include <stdint.h>

#define DM   1024
#define SEQ  2048
#define NH   16
#define DH   64
#define FFD  4096

typedef float  f32x4  __attribute__((ext_vector_type(4)));
typedef float  f32x16 __attribute__((ext_vector_type(16)));
typedef __bf16 bf16x8 __attribute__((ext_vector_type(8)));
typedef unsigned short u16;
typedef unsigned short u16x4v __attribute__((ext_vector_type(4)));
typedef unsigned short u16x8 __attribute__((ext_vector_type(8)));

__device__ __forceinline__ u16 f2bf(float f){
    unsigned int u = __builtin_bit_cast(unsigned int, f);
    u = u + 0x7FFFu + ((u >> 16) & 1u);   // RNE
    return (u16)(u >> 16);
}
__device__ __forceinline__ float bf2f(u16 v){
    unsigned int u = ((unsigned int)v) << 16;
    return __builtin_bit_cast(float, u);
}
__device__ __forceinline__ f32x4 zero4(){ f32x4 v; v[0]=0.f;v[1]=0.f;v[2]=0.f;v[3]=0.f; return v; }
__device__ __forceinline__ unsigned int cvtpk(float lo, float hi){
    unsigned int r;
    asm("v_cvt_pk_bf16_f32 %0, %1, %2" : "=v"(r) : "v"(lo), "v"(hi));
    return r;
}

__device__ __forceinline__ void gload_lds16(const void* g, void* l){
    __builtin_amdgcn_global_load_lds(
        (const __attribute__((address_space(1))) unsigned int*)(uintptr_t)g,
        (__attribute__((address_space(3))) unsigned int*)(uintptr_t)l,
        16, 0, 0);
}

// ---- all 4 weight transposes in ONE launch: src f32 [K][N] -> dst bf16 [N][K] ----
__global__ __launch_bounds__(256) void transall_k(const float* __restrict__ s0, u16* __restrict__ d0,
                                                  const float* __restrict__ s1, u16* __restrict__ d1,
                                                  const float* __restrict__ s2, u16* __restrict__ d2,
                                                  const float* __restrict__ s3, u16* __restrict__ d3){
    __shared__ float tile[64][65];
    const int b = blockIdx.x;
    const float* src; u16* dst; int K, N, bx, by;
    if (b < 768)      { src = s0; dst = d0; K = 1024; N = 3072; bx = b % 48;          by = b / 48; }
    else if (b < 1024){ src = s1; dst = d1; K = 1024; N = 1024; bx = (b-768) % 16;    by = (b-768) / 16; }
    else if (b < 2048){ src = s2; dst = d2; K = 1024; N = 4096; bx = (b-1024) % 64;   by = (b-1024) / 64; }
    else              { src = s3; dst = d3; K = 4096; N = 1024; bx = (b-2048) % 16;   by = (b-2048) / 16; }
    const int n0 = bx * 64, k0 = by * 64;
    const int t = threadIdx.x;
#pragma unroll
    for (int i = 0; i < 16; ++i){
        int idx = t + i * 256;
        int r = idx >> 6, c = idx & 63;
        tile[r][c] = src[(size_t)(k0 + r) * N + n0 + c];
    }
    __syncthreads();
#pragma unroll
    for (int i = 0; i < 16; ++i){
        int idx = t + i * 256;
        int r = idx >> 6, c = idx & 63;
        dst[(size_t)(n0 + r) * K + k0 + c] = f2bf(tile[c][r]);
    }
}

// ---------------- LayerNorm: fp32 in -> bf16 out, row-per-block, D=1024 ----------------
__global__ __launch_bounds__(256) void ln_k(const float* __restrict__ in,
                                            const float* __restrict__ gw,
                                            const float* __restrict__ bw,
                                            u16* __restrict__ out){
    const int row = blockIdx.x, t = threadIdx.x;
    f32x4 vv = *((const f32x4*)(in + (size_t)row * DM) + t);
    float v[4];
#pragma unroll
    for (int j = 0; j < 4; ++j) v[j] = vv[j];
    float s = 0.f, ss = 0.f;
#pragma unroll
    for (int j = 0; j < 4; ++j){ s += v[j]; ss += v[j] * v[j]; }
#pragma unroll
    for (int off = 1; off < 64; off <<= 1){
        s  += __shfl_xor(s,  off, 64);
        ss += __shfl_xor(ss, off, 64);
    }
    __shared__ float rs_[4], rss_[4];
    const int w = t >> 6;
    if ((t & 63) == 0){ rs_[w] = s; rss_[w] = ss; }
    __syncthreads();
    s  = rs_[0] + rs_[1] + rs_[2] + rs_[3];
    ss = rss_[0] + rss_[1] + rss_[2] + rss_[3];
    const float mean = s * (1.f / DM);
    const float var  = ss * (1.f / DM) - mean * mean;
    const float rstd = rsqrtf(var + 1e-5f);
#pragma unroll
    for (int j = 0; j < 4; ++j){
        int c = t * 4 + j;
        out[(size_t)row * DM + c] = f2bf((v[j] - mean) * rstd * gw[c] + bw[c]);
    }
}

// ---- GEMM: A [M][K] bf16, Bt [N][K] bf16. TMxTN tile, BK-step, global_load_lds + dbuf ----
// 1D XCD-swizzled grid (grid % 8 == 0). EPI: 1 = +bias +fp32 residual, fp32 out;
// 2 = +bias GELU, bf16 out; 3 = +bias +fp32 residual, fp32 out;
// 4 = QKV fused epilogue writing FRAGMENT-MAJOR layouts.
template<int TM, int TN, int WR, int WC, int EPI, int BK = 32>
__global__ __launch_bounds__(256) void gemm_k(const u16* __restrict__ A,
                                              const u16* __restrict__ Bt,
                                              const float* __restrict__ bias,
                                              const float* __restrict__ resid,
                                              void* __restrict__ out,
                                              u16* __restrict__ qout,
                                              u16* __restrict__ kout,
                                              u16* __restrict__ vout,
                                              int M, int N, int K){
    constexpr int MR   = TM / WR / 16;
    constexpr int NR   = TN / WC / 16;
    constexpr int CPR  = BK / 8;             // 16B chunks per row
    constexpr int AISS = (TM * CPR) / 256;   // staging issues for A per K-step
    constexpr int BISS = (TN * CPR) / 256;
    __shared__ u16 ldsAll[2 * TM * BK + 2 * TN * BK];
    u16* ldsA = ldsAll;
    u16* ldsB = ldsAll + 2 * TM * BK;
    const int t = threadIdx.x;
    const int L = t & 63, w = t >> 6;
    const int g = L >> 4, li = L & 15;
    const int wr = w / WC, wc = w % WC;
    const int rowbase = wr * (TM / WR);
    const int colbase = wc * (TN / WC);
    const int nxb  = M / TM;
    const int nper = (int)gridDim.x >> 3;
    const int jswz = ((int)blockIdx.x & 7) * nper + ((int)blockIdx.x >> 3);
    const int brow = (jswz % nxb) * TM, bcol = (jswz / nxb) * TN;

    const u16* aPtr = A  + (size_t)brow * K;
    const u16* bPtr = Bt + (size_t)bcol * K;

    f32x4 acc[MR][NR];
#pragma unroll
    for (int m = 0; m < MR; ++m)
#pragma unroll
        for (int n = 0; n < NR; ++n) acc[m][n] = zero4();

    auto STAGE = [&](int buf, int ko){
#pragma unroll
        for (int i = 0; i < AISS; ++i){
            int o = i * 256 + t;
            gload_lds16(aPtr + (size_t)(o / CPR) * K + (o % CPR) * 8 + ko, &ldsA[buf * TM * BK + o * 8]);
        }
#pragma unroll
        for (int i = 0; i < BISS; ++i){
            int o = i * 256 + t;
            gload_lds16(bPtr + (size_t)(o / CPR) * K + (o % CPR) * 8 + ko, &ldsB[buf * TN * BK + o * 8]);
        }
    };

    const int KT = K / BK;
    int cur = 0;
    STAGE(0, 0);
    __syncthreads();
    for (int kt = 0; kt < KT; ++kt){
        if (kt + 1 < KT) STAGE(cur ^ 1, (kt + 1) * BK);
#pragma unroll
        for (int kk = 0; kk < BK / 32; ++kk){
            bf16x8 af[MR], bfr[NR];
#pragma unroll
            for (int m = 0; m < MR; ++m)
                af[m]  = *(const bf16x8*)&ldsA[cur * TM * BK + (rowbase + m * 16 + li) * BK + kk * 32 + g * 8];
#pragma unroll
            for (int n = 0; n < NR; ++n)
                bfr[n] = *(const bf16x8*)&ldsB[cur * TN * BK + (colbase + n * 16 + li) * BK + kk * 32 + g * 8];
#pragma unroll
            for (int m = 0; m < MR; ++m)
#pragma unroll
                for (int n = 0; n < NR; ++n)
                    acc[m][n] = __builtin_amdgcn_mfma_f32_16x16x32_bf16(af[m], bfr[n], acc[m][n], 0, 0, 0);
        }
        __syncthreads();
        cur ^= 1;
    }

    if constexpr (EPI == 4){
        const int colabs = bcol + colbase;
        const int part = colabs >> 10;          // 0=Q, 1=K, 2=V
        if (part < 2){
            u16* dst = (part == 0) ? qout : kout;
            const int h = (colabs >> 6) & 15;
            float freq[2];
#pragma unroll
            for (int n = 0; n < 2; ++n)
                freq[n] = powf(10000.f, -(float)(n * 16 + li) * (1.f / 32.f));
#pragma unroll
            for (int m = 0; m < MR; ++m)
#pragma unroll
                for (int r = 0; r < 4; ++r){
                    const int srow = brow + rowbase + m * 16 + g * 4 + r;
                    const size_t tb = (size_t)(h * 64 + (srow >> 5)) * 2048
                                    + (li >> 3) * 256 + (srow & 31) * 8 + (li & 7);
#pragma unroll
                    for (int n = 0; n < 2; ++n){
                        float lo = acc[m][n][r], hi = acc[m][n + 2][r];
                        float sn, cs;
                        sincosf((float)srow * freq[n], &sn, &cs);
                        dst[tb + n * 512]       = f2bf(lo * cs - hi * sn);
                        dst[tb + (n + 2) * 512] = f2bf(hi * cs + lo * sn);
                    }
                }
        } else {
            u16* tileT = ldsAll;                 // 128*72 u16 = 18KB
            __syncthreads();
#pragma unroll
            for (int m = 0; m < MR; ++m)
#pragma unroll
                for (int n = 0; n < NR; ++n)
#pragma unroll
                    for (int r = 0; r < 4; ++r){
                        const int row = rowbase + m * 16 + g * 4 + r;   // s-local
                        const int col = colbase + n * 16 + li;          // dv-local
                        tileT[col * 72 + row] = f2bf(acc[m][n][r]);
                    }
            __syncthreads();
            const int dv = t >> 1, half = t & 1;
            const int habs = ((bcol + dv) >> 6) & 15;
            const int dvl = dv & 63;
            const int f = dvl >> 5, dv5 = dvl & 31;
            const int tt = (brow >> 5) + half;
            u16* vbase = vout + (size_t)(habs * 64 + tt) * 2048 + f * 256 + dv5 * 8;
#pragma unroll
            for (int j = 0; j < 4; ++j)
                *(u16x8*)(vbase + (j >> 1) * 1024 + (j & 1) * 512)
                    = *(const u16x8*)&tileT[dv * 72 + half * 32 + j * 8];
        }
        return;
    }

#pragma unroll
    for (int m = 0; m < MR; ++m)
#pragma unroll
        for (int n = 0; n < NR; ++n)
#pragma unroll
            for (int r = 0; r < 4; ++r){
                const int row = brow + rowbase + m * 16 + g * 4 + r;
                const int col = bcol + colbase + n * 16 + li;
                float v = acc[m][n][r];
                if constexpr (EPI == 1){
                    v += bias[col] + resid[(size_t)row * N + col];
                    ((float*)out)[(size_t)row * N + col] = v;
                } else if constexpr (EPI == 2){
                    v += bias[col];
                    v = 0.5f * v * (1.f + erff(v * 0.70710678f));
                    ((u16*)out)[(size_t)row * N + col] = f2bf(v);
                } else {
                    v += bias[col] + resid[(size_t)row * N + col];
                    ((float*)out)[(size_t)row * N + col] = v;
                }
            }
}

// -------- causal flash attention: 32x32 swapped-QK^T, FRAGMENT-MAJOR loads --------
#define CHT 8   // kv-tiles (32 wide) per chunk
__global__ __launch_bounds__(256) void attn_k(const u16* __restrict__ Qh,
                                              const u16* __restrict__ Kh,
                                              const u16* __restrict__ VT,
                                              u16* __restrict__ Opart,
                                              float* __restrict__ ml){
    const int t = threadIdx.x, w = t >> 6, L = t & 63;
    const int bid = blockIdx.x;
    const int xcd = bid & 7;
    const int lj  = (bid >> 3) * 4 + w;       // 0..575 within XCD
    const int h   = xcd * 2 + (lj & 1);
    const int jd  = lj >> 1;                  // 0..287, ascending = longest-first
    int g = 7, rem = jd;
    while (rem >= 8 * (g + 1)){ rem -= 8 * (g + 1); --g; }
    const int gp1 = g + 1;
    const int qt = 8 * g + 7 - rem / gp1;
    const int c  = rem % gp1;
    const int t0 = c * CHT;
    const int tEnd = min(t0 + CHT, qt + 1);
    const int l31 = L & 31, H = L >> 5;

    const size_t hT = (size_t)h * 64;
    const int lane_off = H * 256 + l31 * 8;
    const int vlane_off = H * 512 + l31 * 8;

    const u16* qB = Qh + (hT + qt) * 2048 + lane_off;
    bf16x8 qf0 = *(const bf16x8*)(qB);
    bf16x8 qf1 = *(const bf16x8*)(qB + 512);
    bf16x8 qf2 = *(const bf16x8*)(qB + 1024);
    bf16x8 qf3 = *(const bf16x8*)(qB + 1536);

    const u16* kB0 = Kh + (hT + t0) * 2048 + lane_off;
    bf16x8 kc0 = *(const bf16x8*)(kB0);
    bf16x8 kc1 = *(const bf16x8*)(kB0 + 512);
    bf16x8 kc2 = *(const bf16x8*)(kB0 + 1024);
    bf16x8 kc3 = *(const bf16x8*)(kB0 + 1536);

    f32x16 O0, O1;
#pragma unroll
    for (int i = 0; i < 16; ++i){ O0[i] = 0.f; O1[i] = 0.f; }
    float m = -3.0e4f, lsum = 0.f;

    for (int tt = t0; tt < tEnd; ++tt){
        const u16* vB = VT + (hT + tt) * 2048 + vlane_off;
        bf16x8 v00 = *(const bf16x8*)(vB);
        bf16x8 v01 = *(const bf16x8*)(vB + 1024);
        bf16x8 v10 = *(const bf16x8*)(vB + 256);
        bf16x8 v11 = *(const bf16x8*)(vB + 1280);

        f32x16 st;
#pragma unroll
        for (int i = 0; i < 16; ++i) st[i] = 0.f;
        st = __builtin_amdgcn_mfma_f32_32x32x16_bf16(kc0, qf0, st, 0, 0, 0);
        st = __builtin_amdgcn_mfma_f32_32x32x16_bf16(kc1, qf1, st, 0, 0, 0);
        st = __builtin_amdgcn_mfma_f32_32x32x16_bf16(kc2, qf2, st, 0, 0, 0);
        st = __builtin_amdgcn_mfma_f32_32x32x16_bf16(kc3, qf3, st, 0, 0, 0);

        const bool more = (tt + 1 < tEnd);
        bf16x8 kn0, kn1, kn2, kn3;
        if (more){
            const u16* kBn = Kh + (hT + tt + 1) * 2048 + lane_off;
            kn0 = *(const bf16x8*)(kBn);
            kn1 = *(const bf16x8*)(kBn + 512);
            kn2 = *(const bf16x8*)(kBn + 1024);
            kn3 = *(const bf16x8*)(kBn + 1536);
        }

        const bool diag = (tt == qt);
        float sv[16];
#pragma unroll
        for (int i = 0; i < 16; ++i){
            float x = st[i] * 0.125f;
            if (diag){
                int kkl = (i & 3) + 8 * (i >> 2) + 4 * H;
                if (kkl > l31) x = -3.0e4f;
            }
            sv[i] = x;
        }
        float smax = sv[0];
#pragma unroll
        for (int i = 1; i < 16; ++i) smax = fmaxf(smax, sv[i]);
        smax = fmaxf(smax, __shfl_xor(smax, 32, 64));
        const float nm = fmaxf(m, smax);
        const float alpha = __expf(m - nm);
        m = nm;
        float ps = 0.f;
#pragma unroll
        for (int i = 0; i < 16; ++i){ sv[i] = __expf(sv[i] - m); ps += sv[i]; }
        ps += __shfl_xor(ps, 32, 64);
        lsum = lsum * alpha + ps;
#pragma unroll
        for (int i = 0; i < 16; ++i){ O0[i] *= alpha; O1[i] *= alpha; }

        unsigned int A0 = cvtpk(sv[0],  sv[1]),  A1 = cvtpk(sv[2],  sv[3]);
        unsigned int B0 = cvtpk(sv[4],  sv[5]),  B1 = cvtpk(sv[6],  sv[7]);
        unsigned int C0 = cvtpk(sv[8],  sv[9]),  C1 = cvtpk(sv[10], sv[11]);
        unsigned int D0 = cvtpk(sv[12], sv[13]), D1 = cvtpk(sv[14], sv[15]);
        unsigned int eA0 = (unsigned int)__shfl_xor((int)A0, 32, 64);
        unsigned int eA1 = (unsigned int)__shfl_xor((int)A1, 32, 64);
        unsigned int eB0 = (unsigned int)__shfl_xor((int)B0, 32, 64);
        unsigned int eB1 = (unsigned int)__shfl_xor((int)B1, 32, 64);
        unsigned int eC0 = (unsigned int)__shfl_xor((int)C0, 32, 64);
        unsigned int eC1 = (unsigned int)__shfl_xor((int)C1, 32, 64);
        unsigned int eD0 = (unsigned int)__shfl_xor((int)D0, 32, 64);
        unsigned int eD1 = (unsigned int)__shfl_xor((int)D1, 32, 64);
        union Uw { unsigned int w[4]; bf16x8 v; };
        Uw f0, f1;
        f0.w[0] = H ? eB0 : A0;  f0.w[1] = H ? eB1 : A1;
        f0.w[2] = H ? B0  : eA0; f0.w[3] = H ? B1  : eA1;
        f1.w[0] = H ? eD0 : C0;  f1.w[1] = H ? eD1 : C1;
        f1.w[2] = H ? D0  : eC0; f1.w[3] = H ? D1  : eC1;

        O0 = __builtin_amdgcn_mfma_f32_32x32x16_bf16(v00, f0.v, O0, 0, 0, 0);
        O0 = __builtin_amdgcn_mfma_f32_32x32x16_bf16(v01, f1.v, O0, 0, 0, 0);
        O1 = __builtin_amdgcn_mfma_f32_32x32x16_bf16(v10, f0.v, O1, 0, 0, 0);
        O1 = __builtin_amdgcn_mfma_f32_32x32x16_bf16(v11, f1.v, O1, 0, 0, 0);

        if (more){ kc0 = kn0; kc1 = kn1; kc2 = kn2; kc3 = kn3; }
    }

    const int jobd = h * 288 + jd;
    const size_t ob = (size_t)jobd * (32 * 64);
    const int q = l31;
#pragma unroll
    for (int f = 0; f < 2; ++f){
        const int dv0 = f * 32;
#pragma unroll
        for (int k = 0; k < 4; ++k){
            u16x4v pkv;
#pragma unroll
            for (int e = 0; e < 4; ++e)
                pkv[e] = f2bf(f == 0 ? O0[k * 4 + e] : O1[k * 4 + e]);
            *(u16x4v*)(Opart + ob + (size_t)q * 64 + dv0 + 8 * k + 4 * H) = pkv;
        }
    }
    if (H == 0){
        ml[((size_t)jobd * 32 + q) * 2]     = m;
        ml[((size_t)jobd * 32 + q) * 2 + 1] = lsum;
    }
}

// -------- combine split-K partials -> att bf16 [S][1024] --------
__global__ __launch_bounds__(256) void combine_k(const u16* __restrict__ Opart,
                                                 const float* __restrict__ ml,
                                                 u16* __restrict__ att){
    const int qt = blockIdx.x, h = blockIdx.y;
    const int g = qt >> 3, gp1 = g + 1;
    const int off = 8 * (36 - ((gp1 * (g + 2)) >> 1));
    const int jd0 = off + (8 * g + 7 - qt) * gp1;
    const int j0 = h * 288 + jd0;
    const int nact = gp1;
    const int t = threadIdx.x;
    const int q = t >> 3, dv0 = (t & 7) * 8;

    float m = -3.0e30f;
    for (int cc = 0; cc < nact; ++cc)
        m = fmaxf(m, ml[((size_t)(j0 + cc) * 32 + q) * 2]);
    float Ls = 0.f;
    float o[8];
#pragma unroll
    for (int j = 0; j < 8; ++j) o[j] = 0.f;
    for (int cc = 0; cc < nact; ++cc){
        const float mv = ml[((size_t)(j0 + cc) * 32 + q) * 2];
        const float lv = ml[((size_t)(j0 + cc) * 32 + q) * 2 + 1];
        const float wgt = __expf(mv - m);
        Ls += wgt * lv;
        const u16* src = Opart + ((size_t)(j0 + cc) * 32 + q) * 64 + dv0;
        u16x8 a = *(const u16x8*)src;
#pragma unroll
        for (int e = 0; e < 8; ++e) o[e] += wgt * bf2f(a[e]);
    }
    const float inv = 1.f / Ls;
    const int qg = qt * 32 + q;
#pragma unroll
    for (int j = 0; j < 8; ++j)
        att[(size_t)qg * DM + h * 64 + dv0 + j] = f2bf(o[j] * inv);
}

extern "C" void kernel_launch(void* const* d_in, const int* in_sizes, int n_in,
                              void* d_out, int out_size, void* d_ws, size_t ws_size,
                              hipStream_t stream){
    (void)in_sizes; (void)n_in; (void)out_size; (void)ws_size;
    const float* x      = (const float*)d_in[0];
    const float* w_qkv  = (const float*)d_in[1];
    const float* w_attn = (const float*)d_in[2];
    const float* b_attn = (const float*)d_in[3];
    const float* w_ff1  = (const float*)d_in[4];
    const float* b_ff1  = (const float*)d_in[5];
    const float* w_ff2  = (const float*)d_in[6];
    const float* b_ff2  = (const float*)d_in[7];
    const float* ln1g   = (const float*)d_in[8];
    const float* ln1b   = (const float*)d_in[9];
    const float* ln2g   = (const float*)d_in[10];
    const float* ln2b   = (const float*)d_in[11];

    // ~61MB workspace, liveness-scheduled (R18 layout; Qh/Kh/VT fragment-major).
    char* ws = (char*)d_ws;
    const size_t MB = 1u << 20;
    u16*   T1    = (u16*)(ws + 0);        // wTqkv  [3072][1024]  0-6MB   (dead after gemm0)
    u16*   T2    = (u16*)(ws + 6  * MB);  // wTattn [1024][1024]  6-8MB   (dead after proj)
    u16*   T3    = (u16*)(ws + 8  * MB);  // wTff1  [4096][1024]  8-16MB  (dead after FF1)
    u16*   T4    = (u16*)(ws + 16 * MB);  // wTff2  [1024][4096]  16-24MB (dead after FF2)
    u16*   h1    = (u16*)(ws + 24 * MB);  // [2048][1024]         24-28MB (dead after gemm0)
    u16*   Qh    = (u16*)(ws + 28 * MB);  // QF frag-major 4MB    28-32MB (dead after attn)
    u16*   Kh    = (u16*)(ws + 32 * MB);  // KF frag-major 4MB    32-36MB (dead after attn)
    u16*   VT    = (u16*)(ws + 36 * MB);  // VF frag-major 4MB    36-40MB (dead after attn)
    u16*   Opart = (u16*)(ws + 40 * MB);  // bf16 16*288 x 32x64  40-59MB (dead after combine)
    float* mlbuf = (float*)(ws + 59 * MB);// f32  16*288 x 32 x 2 59-60.2MB
    u16*   att   = (u16*)(ws + 0);        // [2048][1024]         0-4MB  (T1 dead)
    float* x2    = (float*)(ws + 40 * MB);// f32 [2048][1024]     40-48MB (Opart dead; live to FF2)
    u16*   h2    = (u16*)(ws + 4  * MB);  // [2048][1024]         4-8MB  (T2 dead)
    u16*   ff    = (u16*)(ws + 24 * MB);  // [2048][4096]         24-40MB (h1/Qh/Kh/VT dead)

    transall_k<<<3072, 256, 0, stream>>>(w_qkv, T1, w_attn, T2, w_ff1, T3, w_ff2, T4);
    ln_k<<<SEQ, 256, 0, stream>>>(x, ln1g, ln1b, h1);
    gemm_k<64,128,2,2,4,64><<<768, 256, 0, stream>>>(h1, T1, nullptr, nullptr, nullptr,
                                                     Qh, Kh, VT, SEQ, 3072, 1024);
    attn_k<<<1152, 256, 0, stream>>>(Qh, Kh, VT, Opart, mlbuf);
    combine_k<<<dim3(64, 16), 256, 0, stream>>>(Opart, mlbuf, att);
    gemm_k<64,64,2,2,1,64><<<512, 256, 0, stream>>>(att, T2, b_attn, x, x2,
                                                    nullptr, nullptr, nullptr, SEQ, 1024, 1024);
    ln_k<<<SEQ, 256, 0, stream>>>(x2, ln2g, ln2b, h2);
    gemm_k<64,128,1,4,2,64><<<1024, 256, 0, stream>>>(h2, T3, b_ff1, nullptr, ff,
                                                      nullptr, nullptr, nullptr, SEQ, 4096, 1024);
    gemm_k<64,64,2,2,3,64><<<512, 256, 0, stream>>>(ff, T4, b_ff2, x2, (float*)d_out,
                                                    nullptr, nullptr, nullptr, SEQ, 1024, 4096);
}

// Round 25
// 168.811 us; speedup vs baseline: 1.0257x; 1.0257x over previous
//
#include <hip/hip_runtime.h>
#include <hip/hip_bf16.h>
#include <stdint.h>

#define DM   1024
#define SEQ  2048
#define NH   16
#define DH   64
#define FFD  4096

typedef float  f32x4  __attribute__((ext_vector_type(4)));
typedef float  f32x16 __attribute__((ext_vector_type(16)));
typedef __bf16 bf16x8 __attribute__((ext_vector_type(8)));
typedef unsigned short u16;
typedef unsigned short u16x4v __attribute__((ext_vector_type(4)));
typedef unsigned short u16x8 __attribute__((ext_vector_type(8)));

__device__ __forceinline__ u16 f2bf(float f){
    unsigned int u = __builtin_bit_cast(unsigned int, f);
    u = u + 0x7FFFu + ((u >> 16) & 1u);   // RNE
    return (u16)(u >> 16);
}
__device__ __forceinline__ float bf2f(u16 v){
    unsigned int u = ((unsigned int)v) << 16;
    return __builtin_bit_cast(float, u);
}
__device__ __forceinline__ f32x4 zero4(){ f32x4 v; v[0]=0.f;v[1]=0.f;v[2]=0.f;v[3]=0.f; return v; }
__device__ __forceinline__ unsigned int cvtpk(float lo, float hi){
    unsigned int r;
    asm("v_cvt_pk_bf16_f32 %0, %1, %2" : "=v"(r) : "v"(lo), "v"(hi));
    return r;
}

__device__ __forceinline__ void gload_lds16(const void* g, void* l){
    __builtin_amdgcn_global_load_lds(
        (const __attribute__((address_space(1))) unsigned int*)(uintptr_t)g,
        (__attribute__((address_space(3))) unsigned int*)(uintptr_t)l,
        16, 0, 0);
}

// ---- all 4 weight transposes in ONE launch: src f32 [K][N] -> dst bf16 [N][K] ----
__global__ __launch_bounds__(256) void transall_k(const float* __restrict__ s0, u16* __restrict__ d0,
                                                  const float* __restrict__ s1, u16* __restrict__ d1,
                                                  const float* __restrict__ s2, u16* __restrict__ d2,
                                                  const float* __restrict__ s3, u16* __restrict__ d3){
    __shared__ float tile[64][65];
    const int b = blockIdx.x;
    const float* src; u16* dst; int K, N, bx, by;
    if (b < 768)      { src = s0; dst = d0; K = 1024; N = 3072; bx = b % 48;          by = b / 48; }
    else if (b < 1024){ src = s1; dst = d1; K = 1024; N = 1024; bx = (b-768) % 16;    by = (b-768) / 16; }
    else if (b < 2048){ src = s2; dst = d2; K = 1024; N = 4096; bx = (b-1024) % 64;   by = (b-1024) / 64; }
    else              { src = s3; dst = d3; K = 4096; N = 1024; bx = (b-2048) % 16;   by = (b-2048) / 16; }
    const int n0 = bx * 64, k0 = by * 64;
    const int t = threadIdx.x;
#pragma unroll
    for (int i = 0; i < 16; ++i){
        int idx = t + i * 256;
        int r = idx >> 6, c = idx & 63;
        tile[r][c] = src[(size_t)(k0 + r) * N + n0 + c];
    }
    __syncthreads();
#pragma unroll
    for (int i = 0; i < 16; ++i){
        int idx = t + i * 256;
        int r = idx >> 6, c = idx & 63;
        dst[(size_t)(n0 + r) * K + k0 + c] = f2bf(tile[c][r]);
    }
}

// ---------------- LayerNorm: fp32 in -> bf16 out, row-per-block, D=1024 ----------------
__global__ __launch_bounds__(256) void ln_k(const float* __restrict__ in,
                                            const float* __restrict__ gw,
                                            const float* __restrict__ bw,
                                            u16* __restrict__ out){
    const int row = blockIdx.x, t = threadIdx.x;
    f32x4 vv = *((const f32x4*)(in + (size_t)row * DM) + t);
    float v[4];
#pragma unroll
    for (int j = 0; j < 4; ++j) v[j] = vv[j];
    float s = 0.f, ss = 0.f;
#pragma unroll
    for (int j = 0; j < 4; ++j){ s += v[j]; ss += v[j] * v[j]; }
#pragma unroll
    for (int off = 1; off < 64; off <<= 1){
        s  += __shfl_xor(s,  off, 64);
        ss += __shfl_xor(ss, off, 64);
    }
    __shared__ float rs_[4], rss_[4];
    const int w = t >> 6;
    if ((t & 63) == 0){ rs_[w] = s; rss_[w] = ss; }
    __syncthreads();
    s  = rs_[0] + rs_[1] + rs_[2] + rs_[3];
    ss = rss_[0] + rss_[1] + rss_[2] + rss_[3];
    const float mean = s * (1.f / DM);
    const float var  = ss * (1.f / DM) - mean * mean;
    const float rstd = rsqrtf(var + 1e-5f);
#pragma unroll
    for (int j = 0; j < 4; ++j){
        int c = t * 4 + j;
        out[(size_t)row * DM + c] = f2bf((v[j] - mean) * rstd * gw[c] + bw[c]);
    }
}

// ---- GEMM: A [M][K] bf16, Bt [N][K] bf16. TMxTN tile, BK-step, global_load_lds + dbuf ----
// 1D XCD-swizzled grid (grid % 8 == 0). EPI: 1 = +bias +fp32 residual, fp32 out;
// 2 = +bias GELU, bf16 out; 3 = +bias +fp32 residual, fp32 out;
// 4 = QKV fused epilogue writing FRAGMENT-MAJOR layouts.
template<int TM, int TN, int WR, int WC, int EPI, int BK = 32>
__global__ __launch_bounds__(256) void gemm_k(const u16* __restrict__ A,
                                              const u16* __restrict__ Bt,
                                              const float* __restrict__ bias,
                                              const float* __restrict__ resid,
                                              void* __restrict__ out,
                                              u16* __restrict__ qout,
                                              u16* __restrict__ kout,
                                              u16* __restrict__ vout,
                                              int M, int N, int K){
    constexpr int MR   = TM / WR / 16;
    constexpr int NR   = TN / WC / 16;
    constexpr int CPR  = BK / 8;             // 16B chunks per row
    constexpr int AISS = (TM * CPR) / 256;   // staging issues for A per K-step
    constexpr int BISS = (TN * CPR) / 256;
    __shared__ u16 ldsAll[2 * TM * BK + 2 * TN * BK];
    u16* ldsA = ldsAll;
    u16* ldsB = ldsAll + 2 * TM * BK;
    const int t = threadIdx.x;
    const int L = t & 63, w = t >> 6;
    const int g = L >> 4, li = L & 15;
    const int wr = w / WC, wc = w % WC;
    const int rowbase = wr * (TM / WR);
    const int colbase = wc * (TN / WC);
    const int nxb  = M / TM;
    const int nper = (int)gridDim.x >> 3;
    const int jswz = ((int)blockIdx.x & 7) * nper + ((int)blockIdx.x >> 3);
    const int brow = (jswz % nxb) * TM, bcol = (jswz / nxb) * TN;

    const u16* aPtr = A  + (size_t)brow * K;
    const u16* bPtr = Bt + (size_t)bcol * K;

    f32x4 acc[MR][NR];
#pragma unroll
    for (int m = 0; m < MR; ++m)
#pragma unroll
        for (int n = 0; n < NR; ++n) acc[m][n] = zero4();

    auto STAGE = [&](int buf, int ko){
#pragma unroll
        for (int i = 0; i < AISS; ++i){
            int o = i * 256 + t;
            gload_lds16(aPtr + (size_t)(o / CPR) * K + (o % CPR) * 8 + ko, &ldsA[buf * TM * BK + o * 8]);
        }
#pragma unroll
        for (int i = 0; i < BISS; ++i){
            int o = i * 256 + t;
            gload_lds16(bPtr + (size_t)(o / CPR) * K + (o % CPR) * 8 + ko, &ldsB[buf * TN * BK + o * 8]);
        }
    };

    const int KT = K / BK;
    int cur = 0;
    STAGE(0, 0);
    __syncthreads();
    for (int kt = 0; kt < KT; ++kt){
        if (kt + 1 < KT) STAGE(cur ^ 1, (kt + 1) * BK);
#pragma unroll
        for (int kk = 0; kk < BK / 32; ++kk){
            bf16x8 af[MR], bfr[NR];
#pragma unroll
            for (int m = 0; m < MR; ++m)
                af[m]  = *(const bf16x8*)&ldsA[cur * TM * BK + (rowbase + m * 16 + li) * BK + kk * 32 + g * 8];
#pragma unroll
            for (int n = 0; n < NR; ++n)
                bfr[n] = *(const bf16x8*)&ldsB[cur * TN * BK + (colbase + n * 16 + li) * BK + kk * 32 + g * 8];
#pragma unroll
            for (int m = 0; m < MR; ++m)
#pragma unroll
                for (int n = 0; n < NR; ++n)
                    acc[m][n] = __builtin_amdgcn_mfma_f32_16x16x32_bf16(af[m], bfr[n], acc[m][n], 0, 0, 0);
        }
        __syncthreads();
        cur ^= 1;
    }

    if constexpr (EPI == 4){
        const int colabs = bcol + colbase;
        const int part = colabs >> 10;          // 0=Q, 1=K, 2=V
        if (part < 2){
            u16* dst = (part == 0) ? qout : kout;
            const int h = (colabs >> 6) & 15;
            float freq[2];
#pragma unroll
            for (int n = 0; n < 2; ++n)
                freq[n] = powf(10000.f, -(float)(n * 16 + li) * (1.f / 32.f));
#pragma unroll
            for (int m = 0; m < MR; ++m)
#pragma unroll
                for (int r = 0; r < 4; ++r){
                    const int srow = brow + rowbase + m * 16 + g * 4 + r;
                    const size_t tb = (size_t)(h * 64 + (srow >> 5)) * 2048
                                    + (li >> 3) * 256 + (srow & 31) * 8 + (li & 7);
#pragma unroll
                    for (int n = 0; n < 2; ++n){
                        float lo = acc[m][n][r], hi = acc[m][n + 2][r];
                        float sn, cs;
                        sincosf((float)srow * freq[n], &sn, &cs);
                        dst[tb + n * 512]       = f2bf(lo * cs - hi * sn);
                        dst[tb + (n + 2) * 512] = f2bf(hi * cs + lo * sn);
                    }
                }
        } else {
            u16* tileT = ldsAll;                 // 128*72 u16 = 18KB
            __syncthreads();
#pragma unroll
            for (int m = 0; m < MR; ++m)
#pragma unroll
                for (int n = 0; n < NR; ++n)
#pragma unroll
                    for (int r = 0; r < 4; ++r){
                        const int row = rowbase + m * 16 + g * 4 + r;   // s-local
                        const int col = colbase + n * 16 + li;          // dv-local
                        tileT[col * 72 + row] = f2bf(acc[m][n][r]);
                    }
            __syncthreads();
            const int dv = t >> 1, half = t & 1;
            const int habs = ((bcol + dv) >> 6) & 15;
            const int dvl = dv & 63;
            const int f = dvl >> 5, dv5 = dvl & 31;
            const int tt = (brow >> 5) + half;
            u16* vbase = vout + (size_t)(habs * 64 + tt) * 2048 + f * 256 + dv5 * 8;
#pragma unroll
            for (int j = 0; j < 4; ++j)
                *(u16x8*)(vbase + (j >> 1) * 1024 + (j & 1) * 512)
                    = *(const u16x8*)&tileT[dv * 72 + half * 32 + j * 8];
        }
        return;
    }

#pragma unroll
    for (int m = 0; m < MR; ++m)
#pragma unroll
        for (int n = 0; n < NR; ++n)
#pragma unroll
            for (int r = 0; r < 4; ++r){
                const int row = brow + rowbase + m * 16 + g * 4 + r;
                const int col = bcol + colbase + n * 16 + li;
                float v = acc[m][n][r];
                if constexpr (EPI == 1){
                    v += bias[col] + resid[(size_t)row * N + col];
                    ((float*)out)[(size_t)row * N + col] = v;
                } else if constexpr (EPI == 2){
                    v += bias[col];
                    v = 0.5f * v * (1.f + erff(v * 0.70710678f));
                    ((u16*)out)[(size_t)row * N + col] = f2bf(v);
                } else {
                    v += bias[col] + resid[(size_t)row * N + col];
                    ((float*)out)[(size_t)row * N + col] = v;
                }
            }
}

// -------- causal flash attention: 32x32 swapped-QK^T, FRAGMENT-MAJOR loads --------
#define CHT 8   // kv-tiles (32 wide) per chunk
__global__ __launch_bounds__(256) void attn_k(const u16* __restrict__ Qh,
                                              const u16* __restrict__ Kh,
                                              const u16* __restrict__ VT,
                                              u16* __restrict__ Opart,
                                              float* __restrict__ ml){
    const int t = threadIdx.x, w = t >> 6, L = t & 63;
    const int bid = blockIdx.x;
    const int xcd = bid & 7;
    const int lj  = (bid >> 3) * 4 + w;       // 0..575 within XCD
    const int h   = xcd * 2 + (lj & 1);
    const int jd  = lj >> 1;                  // 0..287, ascending = longest-first
    int g = 7, rem = jd;
    while (rem >= 8 * (g + 1)){ rem -= 8 * (g + 1); --g; }
    const int gp1 = g + 1;
    const int qt = 8 * g + 7 - rem / gp1;
    const int c  = rem % gp1;
    const int t0 = c * CHT;
    const int tEnd = min(t0 + CHT, qt + 1);
    const int l31 = L & 31, H = L >> 5;

    const size_t hT = (size_t)h * 64;
    const int lane_off = H * 256 + l31 * 8;
    const int vlane_off = H * 512 + l31 * 8;

    const u16* qB = Qh + (hT + qt) * 2048 + lane_off;
    bf16x8 qf0 = *(const bf16x8*)(qB);
    bf16x8 qf1 = *(const bf16x8*)(qB + 512);
    bf16x8 qf2 = *(const bf16x8*)(qB + 1024);
    bf16x8 qf3 = *(const bf16x8*)(qB + 1536);

    const u16* kB0 = Kh + (hT + t0) * 2048 + lane_off;
    bf16x8 kc0 = *(const bf16x8*)(kB0);
    bf16x8 kc1 = *(const bf16x8*)(kB0 + 512);
    bf16x8 kc2 = *(const bf16x8*)(kB0 + 1024);
    bf16x8 kc3 = *(const bf16x8*)(kB0 + 1536);

    f32x16 O0, O1;
#pragma unroll
    for (int i = 0; i < 16; ++i){ O0[i] = 0.f; O1[i] = 0.f; }
    float m = -3.0e4f, lsum = 0.f;

    for (int tt = t0; tt < tEnd; ++tt){
        const u16* vB = VT + (hT + tt) * 2048 + vlane_off;
        bf16x8 v00 = *(const bf16x8*)(vB);
        bf16x8 v01 = *(const bf16x8*)(vB + 1024);
        bf16x8 v10 = *(const bf16x8*)(vB + 256);
        bf16x8 v11 = *(const bf16x8*)(vB + 1280);

        f32x16 st;
#pragma unroll
        for (int i = 0; i < 16; ++i) st[i] = 0.f;
        st = __builtin_amdgcn_mfma_f32_32x32x16_bf16(kc0, qf0, st, 0, 0, 0);
        st = __builtin_amdgcn_mfma_f32_32x32x16_bf16(kc1, qf1, st, 0, 0, 0);
        st = __builtin_amdgcn_mfma_f32_32x32x16_bf16(kc2, qf2, st, 0, 0, 0);
        st = __builtin_amdgcn_mfma_f32_32x32x16_bf16(kc3, qf3, st, 0, 0, 0);

        const bool more = (tt + 1 < tEnd);
        bf16x8 kn0, kn1, kn2, kn3;
        if (more){
            const u16* kBn = Kh + (hT + tt + 1) * 2048 + lane_off;
            kn0 = *(const bf16x8*)(kBn);
            kn1 = *(const bf16x8*)(kBn + 512);
            kn2 = *(const bf16x8*)(kBn + 1024);
            kn3 = *(const bf16x8*)(kBn + 1536);
        }

        const bool diag = (tt == qt);
        float sv[16];
#pragma unroll
        for (int i = 0; i < 16; ++i){
            float x = st[i] * 0.125f;
            if (diag){
                int kkl = (i & 3) + 8 * (i >> 2) + 4 * H;
                if (kkl > l31) x = -3.0e4f;
            }
            sv[i] = x;
        }
        float smax = sv[0];
#pragma unroll
        for (int i = 1; i < 16; ++i) smax = fmaxf(smax, sv[i]);
        smax = fmaxf(smax, __shfl_xor(smax, 32, 64));
        const float nm = fmaxf(m, smax);
        const float alpha = __expf(m - nm);
        m = nm;
        float ps = 0.f;
#pragma unroll
        for (int i = 0; i < 16; ++i){ sv[i] = __expf(sv[i] - m); ps += sv[i]; }
        ps += __shfl_xor(ps, 32, 64);
        lsum = lsum * alpha + ps;
#pragma unroll
        for (int i = 0; i < 16; ++i){ O0[i] *= alpha; O1[i] *= alpha; }

        unsigned int A0 = cvtpk(sv[0],  sv[1]),  A1 = cvtpk(sv[2],  sv[3]);
        unsigned int B0 = cvtpk(sv[4],  sv[5]),  B1 = cvtpk(sv[6],  sv[7]);
        unsigned int C0 = cvtpk(sv[8],  sv[9]),  C1 = cvtpk(sv[10], sv[11]);
        unsigned int D0 = cvtpk(sv[12], sv[13]), D1 = cvtpk(sv[14], sv[15]);
        unsigned int eA0 = (unsigned int)__shfl_xor((int)A0, 32, 64);
        unsigned int eA1 = (unsigned int)__shfl_xor((int)A1, 32, 64);
        unsigned int eB0 = (unsigned int)__shfl_xor((int)B0, 32, 64);
        unsigned int eB1 = (unsigned int)__shfl_xor((int)B1, 32, 64);
        unsigned int eC0 = (unsigned int)__shfl_xor((int)C0, 32, 64);
        unsigned int eC1 = (unsigned int)__shfl_xor((int)C1, 32, 64);
        unsigned int eD0 = (unsigned int)__shfl_xor((int)D0, 32, 64);
        unsigned int eD1 = (unsigned int)__shfl_xor((int)D1, 32, 64);
        union Uw { unsigned int w[4]; bf16x8 v; };
        Uw f0, f1;
        f0.w[0] = H ? eB0 : A0;  f0.w[1] = H ? eB1 : A1;
        f0.w[2] = H ? B0  : eA0; f0.w[3] = H ? B1  : eA1;
        f1.w[0] = H ? eD0 : C0;  f1.w[1] = H ? eD1 : C1;
        f1.w[2] = H ? D0  : eC0; f1.w[3] = H ? D1  : eC1;

        O0 = __builtin_amdgcn_mfma_f32_32x32x16_bf16(v00, f0.v, O0, 0, 0, 0);
        O0 = __builtin_amdgcn_mfma_f32_32x32x16_bf16(v01, f1.v, O0, 0, 0, 0);
        O1 = __builtin_amdgcn_mfma_f32_32x32x16_bf16(v10, f0.v, O1, 0, 0, 0);
        O1 = __builtin_amdgcn_mfma_f32_32x32x16_bf16(v11, f1.v, O1, 0, 0, 0);

        if (more){ kc0 = kn0; kc1 = kn1; kc2 = kn2; kc3 = kn3; }
    }

    const int jobd = h * 288 + jd;
    const size_t ob = (size_t)jobd * (32 * 64);
    const int q = l31;
#pragma unroll
    for (int f = 0; f < 2; ++f){
        const int dv0 = f * 32;
#pragma unroll
        for (int k = 0; k < 4; ++k){
            u16x4v pkv;
#pragma unroll
            for (int e = 0; e < 4; ++e)
                pkv[e] = f2bf(f == 0 ? O0[k * 4 + e] : O1[k * 4 + e]);
            *(u16x4v*)(Opart + ob + (size_t)q * 64 + dv0 + 8 * k + 4 * H) = pkv;
        }
    }
    if (H == 0){
        ml[((size_t)jobd * 32 + q) * 2]     = m;
        ml[((size_t)jobd * 32 + q) * 2 + 1] = lsum;
    }
}

// -------- combine split-K partials -> att bf16 [S][1024] --------
__global__ __launch_bounds__(256) void combine_k(const u16* __restrict__ Opart,
                                                 const float* __restrict__ ml,
                                                 u16* __restrict__ att){
    const int qt = blockIdx.x, h = blockIdx.y;
    const int g = qt >> 3, gp1 = g + 1;
    const int off = 8 * (36 - ((gp1 * (g + 2)) >> 1));
    const int jd0 = off + (8 * g + 7 - qt) * gp1;
    const int j0 = h * 288 + jd0;
    const int nact = gp1;
    const int t = threadIdx.x;
    const int q = t >> 3, dv0 = (t & 7) * 8;

    float m = -3.0e30f;
    for (int cc = 0; cc < nact; ++cc)
        m = fmaxf(m, ml[((size_t)(j0 + cc) * 32 + q) * 2]);
    float Ls = 0.f;
    float o[8];
#pragma unroll
    for (int j = 0; j < 8; ++j) o[j] = 0.f;
    for (int cc = 0; cc < nact; ++cc){
        const float mv = ml[((size_t)(j0 + cc) * 32 + q) * 2];
        const float lv = ml[((size_t)(j0 + cc) * 32 + q) * 2 + 1];
        const float wgt = __expf(mv - m);
        Ls += wgt * lv;
        const u16* src = Opart + ((size_t)(j0 + cc) * 32 + q) * 64 + dv0;
        u16x8 a = *(const u16x8*)src;
#pragma unroll
        for (int e = 0; e < 8; ++e) o[e] += wgt * bf2f(a[e]);
    }
    const float inv = 1.f / Ls;
    const int qg = qt * 32 + q;
#pragma unroll
    for (int j = 0; j < 8; ++j)
        att[(size_t)qg * DM + h * 64 + dv0 + j] = f2bf(o[j] * inv);
}

extern "C" void kernel_launch(void* const* d_in, const int* in_sizes, int n_in,
                              void* d_out, int out_size, void* d_ws, size_t ws_size,
                              hipStream_t stream){
    (void)in_sizes; (void)n_in; (void)out_size; (void)ws_size;
    const float* x      = (const float*)d_in[0];
    const float* w_qkv  = (const float*)d_in[1];
    const float* w_attn = (const float*)d_in[2];
    const float* b_attn = (const float*)d_in[3];
    const float* w_ff1  = (const float*)d_in[4];
    const float* b_ff1  = (const float*)d_in[5];
    const float* w_ff2  = (const float*)d_in[6];
    const float* b_ff2  = (const float*)d_in[7];
    const float* ln1g   = (const float*)d_in[8];
    const float* ln1b   = (const float*)d_in[9];
    const float* ln2g   = (const float*)d_in[10];
    const float* ln2b   = (const float*)d_in[11];

    // ~61MB workspace, liveness-scheduled (R18 layout; Qh/Kh/VT fragment-major).
    char* ws = (char*)d_ws;
    const size_t MB = 1u << 20;
    u16*   T1    = (u16*)(ws + 0);        // wTqkv  [3072][1024]  0-6MB   (dead after gemm0)
    u16*   T2    = (u16*)(ws + 6  * MB);  // wTattn [1024][1024]  6-8MB   (dead after proj)
    u16*   T3    = (u16*)(ws + 8  * MB);  // wTff1  [4096][1024]  8-16MB  (dead after FF1)
    u16*   T4    = (u16*)(ws + 16 * MB);  // wTff2  [1024][4096]  16-24MB (dead after FF2)
    u16*   h1    = (u16*)(ws + 24 * MB);  // [2048][1024]         24-28MB (dead after gemm0)
    u16*   Qh    = (u16*)(ws + 28 * MB);  // QF frag-major 4MB    28-32MB (dead after attn)
    u16*   Kh    = (u16*)(ws + 32 * MB);  // KF frag-major 4MB    32-36MB (dead after attn)
    u16*   VT    = (u16*)(ws + 36 * MB);  // VF frag-major 4MB    36-40MB (dead after attn)
    u16*   Opart = (u16*)(ws + 40 * MB);  // bf16 16*288 x 32x64  40-59MB (dead after combine)
    float* mlbuf = (float*)(ws + 59 * MB);// f32  16*288 x 32 x 2 59-60.2MB
    u16*   att   = (u16*)(ws + 0);        // [2048][1024]         0-4MB  (T1 dead)
    float* x2    = (float*)(ws + 40 * MB);// f32 [2048][1024]     40-48MB (Opart dead; live to FF2)
    u16*   h2    = (u16*)(ws + 4  * MB);  // [2048][1024]         4-8MB  (T2 dead)
    u16*   ff    = (u16*)(ws + 24 * MB);  // [2048][4096]         24-40MB (h1/Qh/Kh/VT dead)

    transall_k<<<3072, 256, 0, stream>>>(w_qkv, T1, w_attn, T2, w_ff1, T3, w_ff2, T4);
    ln_k<<<SEQ, 256, 0, stream>>>(x, ln1g, ln1b, h1);
    gemm_k<64,128,2,2,4,64><<<768, 256, 0, stream>>>(h1, T1, nullptr, nullptr, nullptr,
                                                     Qh, Kh, VT, SEQ, 3072, 1024);
    attn_k<<<1152, 256, 0, stream>>>(Qh, Kh, VT, Opart, mlbuf);
    combine_k<<<dim3(64, 16), 256, 0, stream>>>(Opart, mlbuf, att);
    gemm_k<64,64,2,2,1,64><<<512, 256, 0, stream>>>(att, T2, b_attn, x, x2,
                                                    nullptr, nullptr, nullptr, SEQ, 1024, 1024);
    ln_k<<<SEQ, 256, 0, stream>>>(x2, ln2g, ln2b, h2);
    gemm_k<64,128,1,4,2,32><<<1024, 256, 0, stream>>>(h2, T3, b_ff1, nullptr, ff,
                                                      nullptr, nullptr, nullptr, SEQ, 4096, 1024);
    gemm_k<64,64,2,2,3,64><<<512, 256, 0, stream>>>(ff, T4, b_ff2, x2, (float*)d_out,
                                                    nullptr, nullptr, nullptr, SEQ, 1024, 4096);
}